// Round 1
// 413.980 us; speedup vs baseline: 1.0020x; 1.0020x over previous
//
#include <hip/hip_runtime.h>

// Local2DSum: out[b,v,h,s] = log(sum_c exp(x[b,v,h,c]) * exp(acc[v,h,c,s]))
//                          - log(sum_c exp(acc[v,h,c,s]))
// B=64, V=32, H=32, C=256, S=256. Inputs N(0,1) -> exp safe in fp16.
//
// R4: one block per (v,h) (grid 1024, 512 threads, 8 waves). x is read and
// exp'd ONCE per (v,h) (was 2x): HBM traffic 448->384 MB (the floor).
// Same pipelined MFMA core as R3 (ping-pong Bsm, register prefetch of acc,
// XOR-swizzled LDS); Bsm widened to all 256 s-cols. Single-pass epilogue:
// Tsm[256][65] overlays Asm+Bsm, stores are full contiguous 1 KB rows.

typedef _Float16 f16x8 __attribute__((ext_vector_type(8)));
typedef _Float16 f16x2 __attribute__((ext_vector_type(2)));
typedef float f32x4 __attribute__((ext_vector_type(4)));

constexpr int BPITCH = 40;            // f16 per Bsm col (80 B)
constexpr int BBUF   = 256 * BPITCH;  // f16 per buffer (20480 B)

__global__ __launch_bounds__(512, 4)
void logmm_kernel(const float* __restrict__ x,
                  const float* __restrict__ acc,
                  float* __restrict__ out) {
    // LDS: Asm 32768 B | Bsm 2x20480 B | red 2048 B | inv 1024 B  = 76800 B
    // Epilogue overlay: Tsm[256][65] f32 = 66560 B over Asm+Bsm (73728 B).
    __shared__ __align__(16) unsigned char smem[76800];
    _Float16* Asm = (_Float16*)smem;              // exp(x) f16, swizzled
    _Float16* Bsm = (_Float16*)(smem + 32768);    // exp(acc)^T ping-pong
    float*    Tsm = (float*)smem;                 // epilogue [s 0..255][pitch 65]
    float*    red = (float*)(smem + 73728);       // 512 f32 partial denoms
    float*    inv = red + 512;                    // 256 f32 1/denom

    const int tid = threadIdx.x;          // 0..511
    const int vh  = blockIdx.x;           // 0..1023

    const float* xb = x   + (size_t)vh * 256;     // b-stride 262144
    const float* ab = acc + (size_t)vh * 65536;   // [c][s], 256 KB contiguous
    float*       ob = out + (size_t)vh * 256;     // b-stride 262144

    const int col   = tid & 255;          // s column this thread stages
    const int khalf = (tid >> 8) * 16;    // k sub-range 0..15 or 16..31

    // preload acc chunk 0 FIRST: its HBM latency hides under stage A below
    float cur[16], nxt[16];
    #pragma unroll
    for (int i = 0; i < 16; ++i)
        cur[i] = ab[(size_t)(khalf + i) * 256 + col];

    // ---- stage A = exp(x) as f16 into LDS (once), XOR-swizzled 16B blocks ----
    {
        const int half = tid >> 7;            // 0..3
        const int c2   = (tid & 127) * 2;
        const int blk  = c2 >> 3;
        #pragma unroll
        for (int it = 0; it < 16; ++it) {
            int row = it * 4 + half;
            float2 v = *(const float2*)(xb + (size_t)row * 262144 + c2);
            f16x2 pk;
            pk.x = (_Float16)__expf(v.x);
            pk.y = (_Float16)__expf(v.y);
            int pb = blk ^ (row & 7);
            *(f16x2*)(Asm + row * 256 + pb * 8 + (c2 & 7)) = pk;
        }
    }

    const int w  = tid >> 6;              // wave -> s-slice base w*32 (0..7)
    const int l  = tid & 63;
    const int ln = l & 15;
    const int q  = l >> 4;

    f32x4 accv[4][2];
    #pragma unroll
    for (int mt = 0; mt < 4; ++mt)
        #pragma unroll
        for (int nt = 0; nt < 2; ++nt)
            accv[mt][nt] = (f32x4){0.f, 0.f, 0.f, 0.f};

    float csum = 0.f;    // partial denom for column `col` over this thread's k rows

    #pragma unroll
    for (int ch = 0; ch < 8; ++ch) {
        // prefetch next chunk (in flight across exp/pack/barrier/MFMA)
        if (ch < 7) {
            const int c0n = (ch + 1) * 32;
            #pragma unroll
            for (int i = 0; i < 16; ++i)
                nxt[i] = ab[(size_t)(c0n + khalf + i) * 256 + col];
        }
        // process current chunk -> Bsm[buf]
        _Float16* Bb = Bsm + (ch & 1) * BBUF;
        #pragma unroll
        for (int g = 0; g < 2; ++g) {
            f16x8 pk;
            #pragma unroll
            for (int i = 0; i < 8; ++i) {
                float e = __expf(cur[g * 8 + i]);
                csum += e;
                pk[i] = (_Float16)e;
            }
            int G  = (khalf >> 3) + g;               // logical k-group 0..3
            int pg = G ^ ((col >> 2) & 3);           // XOR swizzle
            *(f16x8*)(Bb + col * BPITCH + pg * 8) = pk;
        }
        __syncthreads();   // single barrier: writes visible; prior buf reads reg-complete
        // ---- MFMA step (K=32) ----
        f16x8 bf[2];
        #pragma unroll
        for (int nt = 0; nt < 2; ++nt) {
            int s  = w * 32 + nt * 16 + ln;
            int pg = q ^ ((s >> 2) & 3);
            bf[nt] = *(const f16x8*)(Bb + s * BPITCH + pg * 8);
        }
        f16x8 af[4];
        const int blk = ch * 4 + q;
        #pragma unroll
        for (int mt = 0; mt < 4; ++mt) {
            int r  = mt * 16 + ln;
            int pb = blk ^ (r & 7);
            af[mt] = *(const f16x8*)(Asm + r * 256 + pb * 8);
        }
        #pragma unroll
        for (int mt = 0; mt < 4; ++mt)
            #pragma unroll
            for (int nt = 0; nt < 2; ++nt)
                accv[mt][nt] = __builtin_amdgcn_mfma_f32_16x16x32_f16(
                    af[mt], bf[nt], accv[mt][nt], 0, 0, 0);
        #pragma unroll
        for (int i = 0; i < 16; ++i) cur[i] = nxt[i];
    }

    // ---- denom: reduce the two k-half partials per column -> 1/denom ----
    __syncthreads();                       // all MFMA LDS reads done
    red[tid] = csum;
    __syncthreads();
    if (tid < 256) inv[tid] = 1.0f / (red[tid] + red[tid + 256]);
    __syncthreads();

    // ---- stage C-tile * inv_den into Tsm[s][b] (pitch 65), single pass ----
    #pragma unroll
    for (int nt = 0; nt < 2; ++nt) {
        int sl = w * 32 + nt * 16 + ln;
        float invd = inv[sl];
        #pragma unroll
        for (int mt = 0; mt < 4; ++mt) {
            int b0 = mt * 16 + q * 4;
            f32x4 vv = accv[mt][nt];
            #pragma unroll
            for (int r = 0; r < 4; ++r)
                Tsm[sl * 65 + b0 + r] = vv[r] * invd;
        }
    }
    __syncthreads();

    // ---- coalesced store: each 64-thread group emits one full 1 KB row ----
    const int bq = tid >> 6;      // 0..7
    const int cc = tid & 63;
    const int s0 = cc * 4;
    #pragma unroll
    for (int p = 0; p < 8; ++p) {
        int b = p * 8 + bq;
        float4 o;
        o.x = __logf(Tsm[(s0 + 0) * 65 + b]);
        o.y = __logf(Tsm[(s0 + 1) * 65 + b]);
        o.z = __logf(Tsm[(s0 + 2) * 65 + b]);
        o.w = __logf(Tsm[(s0 + 3) * 65 + b]);
        *(float4*)(ob + (size_t)b * 262144 + s0) = o;
    }
}

extern "C" void kernel_launch(void* const* d_in, const int* in_sizes, int n_in,
                              void* d_out, int out_size, void* d_ws, size_t ws_size,
                              hipStream_t stream) {
    const float* x   = (const float*)d_in[0];   // [64,32,32,256]
    const float* acc = (const float*)d_in[1];   // [32,32,256,256]
    float* out = (float*)d_out;                 // [64,32,32,256]
    logmm_kernel<<<dim3(1024), dim3(512), 0, stream>>>(x, acc, out);
}

// Round 2
// 411.438 us; speedup vs baseline: 1.0081x; 1.0062x over previous
//
#include <hip/hip_runtime.h>

// Local2DSum: out[b,v,h,s] = log(sum_c exp(x[b,v,h,c]) * exp(acc[v,h,c,s]))
//                          - log(sum_c exp(acc[v,h,c,s]))
// B=64, V=32, H=32, C=256, S=256. Inputs N(0,1) -> exp safe in fp16.
//
// R5: same MFMA core as R4 (one block per (v,h), 512 thr, ping-pong Bsm).
// Key fix: in-loop barrier is now an LDS-only drain (asm lgkmcnt(0)+s_barrier)
// instead of __syncthreads(), which hipcc lowers with a full vmcnt(0) drain
// that was killing the acc register prefetch every chunk. Also: kv[2][16]
// register ping-pong (no copy loop), and epilogue transpose tile stored as
// [b][pitch 260] -> conflict-free ds_read_b128 + 1KB/wave float4 stores.

typedef _Float16 f16x8 __attribute__((ext_vector_type(8)));
typedef _Float16 f16x2 __attribute__((ext_vector_type(2)));
typedef float f32x4 __attribute__((ext_vector_type(4)));

constexpr int BPITCH = 40;            // f16 per Bsm col (80 B)
constexpr int BBUF   = 256 * BPITCH;  // f16 per buffer (20480 B)

__global__ __launch_bounds__(512, 4)
void logmm_kernel(const float* __restrict__ x,
                  const float* __restrict__ acc,
                  float* __restrict__ out) {
    // LDS: Asm 32768 | Bsm 2x20480 | red 2048 | inv 1024 = 76800 B
    // Epilogue overlay: Tsm[64][260] f32 = 66560 B over Asm+Bsm (dead then).
    __shared__ __align__(16) unsigned char smem[76800];
    _Float16* Asm = (_Float16*)smem;              // exp(x) f16, swizzled
    _Float16* Bsm = (_Float16*)(smem + 32768);    // exp(acc)^T ping-pong
    float*    Tsm = (float*)smem;                 // epilogue [b 0..63][pitch 260]
    float*    red = (float*)(smem + 73728);       // 512 f32 partial denoms
    float*    inv = red + 512;                    // 256 f32 1/denom

    const int tid = threadIdx.x;          // 0..511
    const int vh  = blockIdx.x;           // 0..1023

    const float* xb = x   + (size_t)vh * 256;     // b-stride 262144
    const float* ab = acc + (size_t)vh * 65536;   // [c][s], 256 KB contiguous
    float*       ob = out + (size_t)vh * 256;     // b-stride 262144

    const int col   = tid & 255;          // s column this thread stages
    const int khalf = (tid >> 8) * 16;    // k sub-range 0..15 or 16..31

    // preload acc chunk 0 FIRST: latency hides under stage A below
    float kv[2][16];
    #pragma unroll
    for (int i = 0; i < 16; ++i)
        kv[0][i] = ab[(size_t)(khalf + i) * 256 + col];

    // ---- stage A = exp(x) as f16 into LDS (once), XOR-swizzled 16B blocks ----
    {
        const int half = tid >> 7;            // 0..3
        const int c2   = (tid & 127) * 2;
        const int blk  = c2 >> 3;
        #pragma unroll
        for (int it = 0; it < 16; ++it) {
            int row = it * 4 + half;
            float2 v = *(const float2*)(xb + (size_t)row * 262144 + c2);
            f16x2 pk;
            pk.x = (_Float16)__expf(v.x);
            pk.y = (_Float16)__expf(v.y);
            int pb = blk ^ (row & 7);
            *(f16x2*)(Asm + row * 256 + pb * 8 + (c2 & 7)) = pk;
        }
    }

    const int w  = tid >> 6;              // wave -> s-slice base w*32 (0..7)
    const int l  = tid & 63;
    const int ln = l & 15;
    const int q  = l >> 4;

    f32x4 accv[4][2];
    #pragma unroll
    for (int mt = 0; mt < 4; ++mt)
        #pragma unroll
        for (int nt = 0; nt < 2; ++nt)
            accv[mt][nt] = (f32x4){0.f, 0.f, 0.f, 0.f};

    float csum = 0.f;    // partial denom for column `col` over this thread's k rows

    #pragma unroll
    for (int ch = 0; ch < 8; ++ch) {
        const int cb = ch & 1;            // compile-time (full unroll)
        // prefetch next chunk (stays in flight across the LDS-only barrier)
        if (ch < 7) {
            const int c0n = (ch + 1) * 32;
            #pragma unroll
            for (int i = 0; i < 16; ++i)
                kv[cb ^ 1][i] = ab[(size_t)(c0n + khalf + i) * 256 + col];
        }
        // process current chunk -> Bsm[buf]
        _Float16* Bb = Bsm + cb * BBUF;
        #pragma unroll
        for (int g = 0; g < 2; ++g) {
            f16x8 pk;
            #pragma unroll
            for (int i = 0; i < 8; ++i) {
                float e = __expf(kv[cb][g * 8 + i]);
                csum += e;
                pk[i] = (_Float16)e;
            }
            int G  = (khalf >> 3) + g;               // logical k-group 0..3
            int pg = G ^ ((col >> 2) & 3);           // XOR swizzle
            *(f16x8*)(Bb + col * BPITCH + pg * 8) = pk;
        }
        // LDS-only barrier: ds_writes visible, global prefetch NOT drained.
        // (Ping-pong safe: each wave's Bsm reads are lgkm-complete before its
        // MFMA, which precedes the next barrier; buffer reuse is at ch+2.)
        asm volatile("s_waitcnt lgkmcnt(0)\n\ts_barrier" ::: "memory");
        // ---- MFMA step (K=32) ----
        f16x8 bf[2];
        #pragma unroll
        for (int nt = 0; nt < 2; ++nt) {
            int s  = w * 32 + nt * 16 + ln;
            int pg = q ^ ((s >> 2) & 3);
            bf[nt] = *(const f16x8*)(Bb + s * BPITCH + pg * 8);
        }
        f16x8 af[4];
        const int blk = ch * 4 + q;
        #pragma unroll
        for (int mt = 0; mt < 4; ++mt) {
            int r  = mt * 16 + ln;
            int pb = blk ^ (r & 7);
            af[mt] = *(const f16x8*)(Asm + r * 256 + pb * 8);
        }
        #pragma unroll
        for (int mt = 0; mt < 4; ++mt)
            #pragma unroll
            for (int nt = 0; nt < 2; ++nt)
                accv[mt][nt] = __builtin_amdgcn_mfma_f32_16x16x32_f16(
                    af[mt], bf[nt], accv[mt][nt], 0, 0, 0);
    }

    // ---- denom: reduce the two k-half partials per column -> 1/denom ----
    __syncthreads();                       // all MFMA LDS reads done
    red[tid] = csum;
    __syncthreads();
    if (tid < 256) inv[tid] = 1.0f / (red[tid] + red[tid + 256]);
    __syncthreads();

    // ---- stage C-tile * inv_den into Tsm[b][s] (pitch 260) ----
    // write pattern: lanes (q) differ by 16 banks -> 2-way (free)
    #pragma unroll
    for (int nt = 0; nt < 2; ++nt) {
        int sl = w * 32 + nt * 16 + ln;
        float invd = inv[sl];
        #pragma unroll
        for (int mt = 0; mt < 4; ++mt) {
            int b0 = mt * 16 + q * 4;
            f32x4 vv = accv[mt][nt];
            #pragma unroll
            for (int r = 0; r < 4; ++r)
                Tsm[(b0 + r) * 260 + sl] = vv[r] * invd;
        }
    }
    __syncthreads();

    // ---- conflict-free b128 reads + 1 KB/wave contiguous float4 stores ----
    #pragma unroll
    for (int it = 0; it < 8; ++it) {
        int idx = it * 512 + tid;
        int b   = idx >> 6;               // wave-uniform row
        int s4  = (idx & 63) * 4;
        f32x4 t = *(const f32x4*)(Tsm + b * 260 + s4);
        float4 o;
        o.x = __logf(t[0]);
        o.y = __logf(t[1]);
        o.z = __logf(t[2]);
        o.w = __logf(t[3]);
        *(float4*)(ob + (size_t)b * 262144 + s4) = o;
    }
}

extern "C" void kernel_launch(void* const* d_in, const int* in_sizes, int n_in,
                              void* d_out, int out_size, void* d_ws, size_t ws_size,
                              hipStream_t stream) {
    const float* x   = (const float*)d_in[0];   // [64,32,32,256]
    const float* acc = (const float*)d_in[1];   // [32,32,256,256]
    float* out = (float*)d_out;                 // [64,32,32,256]
    logmm_kernel<<<dim3(1024), dim3(512), 0, stream>>>(x, acc, out);
}